// Round 12
// baseline (703.585 us; speedup 1.0000x reference)
//
#include <hip/hip_runtime.h>
#include <stdint.h>

#define B_ 32
#define T_ 2048
#define C_ 768
#define H_ 1536
#define L_ 16

typedef unsigned short u16;
typedef __bf16 bf16x8 __attribute__((ext_vector_type(8)));
typedef float f32x4 __attribute__((ext_vector_type(4)));

__device__ __forceinline__ u16 f2bf(float f) {
    union { float f; uint32_t u; } v; v.f = f;
    uint32_t r = (v.u + 0x7fffu + ((v.u >> 16) & 1u)) >> 16;
    return (u16)r;
}

__device__ __forceinline__ float wave_sum(float v) {
    v += __shfl_xor(v, 1);  v += __shfl_xor(v, 2);  v += __shfl_xor(v, 4);
    v += __shfl_xor(v, 8);  v += __shfl_xor(v, 16); v += __shfl_xor(v, 32);
    return v;
}

__global__ void k_cvt(const float* __restrict__ in, u16* __restrict__ out, int n4) {
    int stride = gridDim.x * blockDim.x;
    for (int i = blockIdx.x * blockDim.x + threadIdx.x; i < n4; i += stride) {
        float4 v = reinterpret_cast<const float4*>(in)[i];
        ushort4 o;
        o.x = f2bf(v.x); o.y = f2bf(v.y); o.z = f2bf(v.z); o.w = f2bf(v.w);
        reinterpret_cast<ushort4*>(out)[i] = o;
    }
}

// ---- prep_all: x->bf16 | b0f = b0 + W0@bq (fp32 read, no W0b write) | Wq^T->bf16 ----
__global__ void k_prep_all(const float* __restrict__ x, u16* __restrict__ xb, int n4x,
                           const float* __restrict__ Wq, u16* __restrict__ WqTb,
                           const float* __restrict__ W0,
                           const float* __restrict__ bq, const float* __restrict__ b0,
                           float* __restrict__ b0f, int e0, int e1) {
    const int t = threadIdx.x;
    if (blockIdx.x < (unsigned)e0) {
        // x fp32 -> bf16, streaming
        int stride = e0 * 256;
        for (int i = blockIdx.x * 256 + t; i < n4x; i += stride) {
            float4 v = reinterpret_cast<const float4*>(x)[i];
            ushort4 o;
            o.x = f2bf(v.x); o.y = f2bf(v.y); o.z = f2bf(v.z); o.w = f2bf(v.w);
            reinterpret_cast<ushort4*>(xb)[i] = o;
        }
    } else if (blockIdx.x < (unsigned)e1) {
        // b0f[rr] = b0[rr] + dot(W0[rr,:], bq) in fp32; W0 read warms L3 for k_wf3
        const int w = t >> 6, lane = t & 63;
        const int nWaves = (e1 - e0) * 4;
        const float4* bq4 = reinterpret_cast<const float4*>(bq);
        float4 b4_0 = bq4[lane], b4_1 = bq4[64 + lane], b4_2 = bq4[128 + lane];
        for (int rr = (blockIdx.x - e0) * 4 + w; rr < B_ * H_; rr += nWaves) {
            const float4* src = reinterpret_cast<const float4*>(W0 + (size_t)rr * 768);
            float4 v0 = src[lane], v1 = src[64 + lane], v2 = src[128 + lane];
            float dot = v0.x * b4_0.x + v0.y * b4_0.y + v0.z * b4_0.z + v0.w * b4_0.w
                      + v1.x * b4_1.x + v1.y * b4_1.y + v1.z * b4_1.z + v1.w * b4_1.w
                      + v2.x * b4_2.x + v2.y * b4_2.y + v2.z * b4_2.z + v2.w * b4_2.w;
            dot = wave_sum(dot);
            if (lane == 0) b0f[rr] = b0[rr] + dot;
        }
    } else {
        // WqTb[c][d] = bf16(Wq[d][c]) via 64x64 LDS tiles
        __shared__ u16 tl[64 * 65];
        const int nb = gridDim.x - e1;
        for (int tile = blockIdx.x - e1; tile < 144; tile += nb) {
            int d0 = (tile / 12) * 64, c0 = (tile % 12) * 64;
            __syncthreads();
#pragma unroll
            for (int p = 0; p < 16; ++p) {
                int idx = p * 256 + t;
                int r = idx >> 6, c = idx & 63;
                tl[r * 65 + c] = f2bf(Wq[(size_t)(d0 + r) * 768 + c0 + c]);
            }
            __syncthreads();
#pragma unroll
            for (int p = 0; p < 16; ++p) {
                int idx = p * 256 + t;
                int r = idx >> 6, c = idx & 63;
                WqTb[(size_t)(c0 + r) * 768 + d0 + c] = tl[c * 65 + r];
            }
        }
    }
}

__device__ __forceinline__ void gload16(const u16* g, u16* l) {
    __builtin_amdgcn_global_load_lds((const __attribute__((address_space(1))) void*)g,
                                     (__attribute__((address_space(3))) void*)l, 16, 0, 0);
}

// ==== 256x256 bf16 GEMM core (R8-proven: 1 barrier/K-tile, A 3-buf / B 2-buf) ====
template <int EPI>
__global__ __launch_bounds__(512, 2) void k_gemm9(const u16* __restrict__ Aall,
                                                  const u16* __restrict__ Ball,
                                                  const float* __restrict__ biasall,
                                                  u16* __restrict__ qout,
                                                  float* __restrict__ ph) {
    __shared__ u16 sm[81920];
    const int t = threadIdx.x;
    const int w = t >> 6, lane = t & 63;
    const int wr = w >> 2, wc = w & 3;
    const int l15 = lane & 15, kq = lane >> 4, cx = lane & 7;

    const int gx = gridDim.x, gy = gridDim.y;
    const int nwg = gx * gy * gridDim.z;
    int flat = blockIdx.x + gx * (blockIdx.y + gy * blockIdx.z);
    if ((nwg & 7) == 0) flat = (flat & 7) * (nwg >> 3) + (flat >> 3);
    const int bx = flat % gx;
    const int tmp = flat / gx;
    const int by = tmp % gy;
    const int bz = tmp / gy;

    const int n0 = bx * 256;
    const int m0 = by * 256;
    const u16* A; const u16* Bm; const float* bias;
    if constexpr (EPI == 0) {
        A = Aall + (size_t)m0 * C_;
        Bm = Ball + (size_t)n0 * C_;
        bias = biasall + n0;
    } else {
        A = Aall + ((size_t)bz * T_ + m0) * C_;
        Bm = Ball + ((size_t)bz * H_ + n0) * C_;
        bias = biasall + (size_t)bz * H_ + n0;
    }

    const int rl = (w << 4) + (lane >> 3);
    const int cs = (((lane & 7) ^ ((lane >> 3) & 7)) << 3);
    const int ldst = (w << 10);

    auto stA = [&](int kt, int buf) {
#pragma unroll
        for (int h = 0; h < 2; ++h) {
            const u16* g = A + (size_t)(h * 128 + rl) * C_ + kt * 64 + cs;
            u16* l = sm + buf * 16384 + h * 8192 + ldst;
            gload16(g, l);
            gload16(g + 8 * C_, l + 512);
        }
    };
    auto stB = [&](int kt, int buf) {
#pragma unroll
        for (int h = 0; h < 2; ++h) {
            const u16* g = Bm + (size_t)(h * 128 + rl) * C_ + kt * 64 + cs;
            u16* l = sm + 49152 + buf * 16384 + h * 8192 + ldst;
            gload16(g, l);
            gload16(g + 8 * C_, l + 512);
        }
    };

    f32x4 acc[8][4];
#pragma unroll
    for (int m = 0; m < 8; ++m)
#pragma unroll
        for (int n = 0; n < 4; ++n) acc[m][n] = (f32x4){0.f, 0.f, 0.f, 0.f};

    bf16x8 a0[4][2], a1[4][2], bfr[2][2];

    const int koff0 = ((kq ^ cx) << 3);
    const int koff1 = (((4 + kq) ^ cx) << 3);
    const u16* aB0 = sm + wr * 8192 + l15 * 64 + koff0;
    const u16* aB1 = sm + wr * 8192 + l15 * 64 + koff1;
    const u16* bB0 = sm + 49152 + (wc >> 1) * 8192 + (wc & 1) * 4096 + l15 * 64 + koff0;
    const u16* bB1 = sm + 49152 + (wc >> 1) * 8192 + (wc & 1) * 4096 + l15 * 64 + koff1;

    auto rdB0 = [&](int off) {
        bfr[0][0] = *reinterpret_cast<const bf16x8*>(bB0 + off);
        bfr[1][0] = *reinterpret_cast<const bf16x8*>(bB0 + off + 1024);
        bfr[0][1] = *reinterpret_cast<const bf16x8*>(bB1 + off);
        bfr[1][1] = *reinterpret_cast<const bf16x8*>(bB1 + off + 1024);
    };
    auto rdB1 = [&](int off) {
        bfr[0][0] = *reinterpret_cast<const bf16x8*>(bB0 + off + 2048);
        bfr[1][0] = *reinterpret_cast<const bf16x8*>(bB0 + off + 3072);
        bfr[0][1] = *reinterpret_cast<const bf16x8*>(bB1 + off + 2048);
        bfr[1][1] = *reinterpret_cast<const bf16x8*>(bB1 + off + 3072);
    };
    auto rdA0 = [&](int off) {
#pragma unroll
        for (int mm = 0; mm < 4; ++mm) {
            a0[mm][0] = *reinterpret_cast<const bf16x8*>(aB0 + off + mm * 1024);
            a0[mm][1] = *reinterpret_cast<const bf16x8*>(aB1 + off + mm * 1024);
        }
    };
    auto rdA1 = [&](int off) {
#pragma unroll
        for (int mm = 0; mm < 4; ++mm) {
            a1[mm][0] = *reinterpret_cast<const bf16x8*>(aB0 + off + 4096 + mm * 1024);
            a1[mm][1] = *reinterpret_cast<const bf16x8*>(aB1 + off + 4096 + mm * 1024);
        }
    };
    auto mma16 = [&](bf16x8 (&a)[4][2], int mq, int qn) {
        __builtin_amdgcn_s_setprio(1);
#pragma unroll
        for (int ks = 0; ks < 2; ++ks)
#pragma unroll
            for (int mm = 0; mm < 4; ++mm)
#pragma unroll
                for (int nn = 0; nn < 2; ++nn)
                    acc[mq * 4 + mm][qn * 2 + nn] = __builtin_amdgcn_mfma_f32_16x16x32_bf16(
                        a[mm][ks], bfr[nn][ks], acc[mq * 4 + mm][qn * 2 + nn], 0, 0, 0);
        __builtin_amdgcn_s_setprio(0);
    };

    stA(0, 0); stB(0, 0); stA(1, 1);
    asm volatile("s_waitcnt vmcnt(4)" ::: "memory");
    __builtin_amdgcn_s_barrier();

    int ba = 0;
#pragma unroll 1
    for (int kt = 0; kt < 12; ++kt) {
        const int bb = kt & 1;
        int ban = ba + 2; if (ban >= 3) ban -= 3;
        const bool s2 = (kt + 2 < 12);
        if (kt + 1 < 12) stB(kt + 1, bb ^ 1);
        if (s2) stA(kt + 2, ban);
        const int aoff = ba * 16384;
        const int boff = bb * 16384;
        rdB0(boff);
        rdA0(aoff);
        rdA1(aoff);
        mma16(a0, 0, 0);
        mma16(a1, 1, 0);
        __builtin_amdgcn_sched_barrier(0);
        rdB1(boff);
        mma16(a0, 0, 1);
        mma16(a1, 1, 1);
        if (s2) asm volatile("s_waitcnt vmcnt(4)" ::: "memory");
        else    asm volatile("s_waitcnt vmcnt(0)" ::: "memory");
        __builtin_amdgcn_s_barrier();
        ba = (ba + 1 == 3) ? 0 : ba + 1;
    }

    if constexpr (EPI == 0) {
        const int colb = n0 + wc * 64 + l15;
        const int rowb = m0 + wr * 128 + (kq << 2);
        float bv[4];
#pragma unroll
        for (int n = 0; n < 4; ++n) bv[n] = bias[wc * 64 + n * 16 + l15];
#pragma unroll
        for (int m = 0; m < 8; ++m)
#pragma unroll
            for (int r = 0; r < 4; ++r) {
                size_t ro = (size_t)(rowb + m * 16 + r) * C_;
#pragma unroll
                for (int n = 0; n < 4; ++n)
                    qout[ro + colb + n * 16] = f2bf(acc[m][n][r] + bv[n]);
            }
    } else {
        const int lwin = by * 2 + wr;
#pragma unroll
        for (int n = 0; n < 4; ++n) {
            int cloc = wc * 64 + n * 16 + l15;
            float bv = bias[cloc];
            float s = 0.f;
#pragma unroll
            for (int m = 0; m < 8; ++m)
#pragma unroll
                for (int r = 0; r < 4; ++r) {
                    float v = acc[m][n][r] + bv;
                    s += v / (1.f + __expf(-v));
                }
            s += __shfl_xor(s, 16);
            s += __shfl_xor(s, 32);
            if (kq == 0)
                ph[((size_t)bz * L_ + lwin) * H_ + n0 + cloc] = s * (1.f / 128.f);
        }
    }
}

__device__ __forceinline__ void stage_bf16_gload(const u16* gtile, int ld, u16* Ts,
                                                 int w, int lane) {
    const int r_in = lane >> 3;
    const int c0   = (lane & 7) << 3;
#pragma unroll
    for (int j = 0; j < 4; ++j) {
        int row = ((w << 2) + j) * 8 + r_in;
        const u16* g = gtile + (size_t)row * ld + c0;
        u16* l = Ts + (((w << 2) + j) << 9);
        gload16(g, l);
    }
}

__device__ __forceinline__ void stage_f32_cvt(const float* gtile, int ld, u16* Ts, int t) {
#pragma unroll
    for (int i = 0; i < 8; ++i) {
        int slot = t + (i << 8);
        int row  = slot >> 4;
        int c4   = (slot & 15) << 2;
        float4 v = *reinterpret_cast<const float4*>(gtile + (size_t)row * ld + c4);
        ushort4 o;
        o.x = f2bf(v.x); o.y = f2bf(v.y); o.z = f2bf(v.z); o.w = f2bf(v.w);
        *reinterpret_cast<ushort4*>(&Ts[row * 64 + c4]) = o;
    }
}

__device__ __forceinline__ void mfma_tile(const u16* As, const u16* Bs,
                                          f32x4 (&acc)[4][4], int wr, int wc, int lane) {
#pragma unroll
    for (int ks = 0; ks < 2; ++ks) {
        const int ko = (ks << 5) + ((lane >> 4) << 3);
        bf16x8 a[4], b[4];
#pragma unroll
        for (int m = 0; m < 4; ++m)
            a[m] = *reinterpret_cast<const bf16x8*>(&As[(wr * 64 + m * 16 + (lane & 15)) * 64 + ko]);
#pragma unroll
        for (int n = 0; n < 4; ++n)
            b[n] = *reinterpret_cast<const bf16x8*>(&Bs[(wc * 64 + n * 16 + (lane & 15)) * 64 + ko]);
#pragma unroll
        for (int m = 0; m < 4; ++m)
#pragma unroll
            for (int n = 0; n < 4; ++n)
                acc[m][n] = __builtin_amdgcn_mfma_f32_16x16x32_bf16(a[m], b[n], acc[m][n], 0, 0, 0);
    }
}

// ==== k_wf3: Wf = W0flat[49152,768](fp32, reg-cvt staged) @ WqT -> bf16 ====
// R1-proven 128^2 2-barrier structure (k_gemm1's A-path); LDS-bounce epilogue.
// W0 is L3-warm from prep_all's b0f pass.
__global__ __launch_bounds__(256, 2) void k_wf3(const float* __restrict__ W0,
                                                const u16* __restrict__ WqTb,
                                                u16* __restrict__ Wfb) {
    __shared__ u16 smw[128 * 136];   // 34816 B; staging uses first 32 KB
    u16* As = smw;
    u16* Bs = smw + 8192;
    const int t = threadIdx.x, w = t >> 6, lane = t & 63;
    const int wr = w >> 1, wc = w & 1;
    const int m0 = blockIdx.y * 128;   // flat row (b*H + h)
    const int n0 = blockIdx.x * 128;   // c col

    f32x4 acc[4][4];
#pragma unroll
    for (int m = 0; m < 4; ++m)
#pragma unroll
        for (int n = 0; n < 4; ++n) acc[m][n] = (f32x4){0.f, 0.f, 0.f, 0.f};

    for (int kt = 0; kt < 12; ++kt) {
        stage_f32_cvt(W0 + (size_t)m0 * C_ + kt * 64, C_, As, t);
        stage_bf16_gload(WqTb + (size_t)n0 * C_ + kt * 64, C_, Bs, w, lane);
        __syncthreads();
        mfma_tile(As, Bs, acc, wr, wc, lane);
        __syncthreads();
    }

    // epilogue: acc -> LDS [128][136] -> coalesced 16B stores
    const int lr0 = wr * 64 + ((lane >> 4) << 2);
    const int lc0 = wc * 64 + (lane & 15);
#pragma unroll
    for (int m = 0; m < 4; ++m)
#pragma unroll
        for (int n = 0; n < 4; ++n)
#pragma unroll
            for (int r = 0; r < 4; ++r)
                smw[(lr0 + m * 16 + r) * 136 + lc0 + n * 16] = f2bf(acc[m][n][r]);
    __syncthreads();
    u16* G = Wfb + (size_t)m0 * C_ + n0;
#pragma unroll
    for (int p = 0; p < 8; ++p) {
        int fl = p * 256 + t;
        int row = fl >> 4, c8 = fl & 15;
        f32x4 v = *reinterpret_cast<const f32x4*>(&smw[row * 136 + c8 * 8]);
        *reinterpret_cast<f32x4*>(&G[(size_t)row * C_ + c8 * 8]) = v;
    }
}

// ---------- pass 3a: pooled = pooled_h @ W1[b]^T + b1 ----------
__global__ __launch_bounds__(256) void k_3a(const float* __restrict__ ph,
                                            const float* __restrict__ W1,
                                            const float* __restrict__ b1,
                                            float* __restrict__ pooled) {
    const int t = threadIdx.x, w = t >> 6, lane = t & 63;
    const int b  = blockIdx.y;
    const int cb = blockIdx.x * 16 + w * 4;

    float acc[4][16];
#pragma unroll
    for (int g = 0; g < 4; ++g)
#pragma unroll
        for (int l = 0; l < 16; ++l) acc[g][l] = 0.f;

    for (int i = 0; i < H_ / 256; ++i) {
        int h0 = i * 256 + lane * 4;
        float4 wv[4];
#pragma unroll
        for (int g = 0; g < 4; ++g)
            wv[g] = *reinterpret_cast<const float4*>(W1 + ((size_t)b * C_ + cb + g) * H_ + h0);
#pragma unroll
        for (int l = 0; l < 16; ++l) {
            float4 pv = *reinterpret_cast<const float4*>(ph + ((size_t)b * L_ + l) * H_ + h0);
#pragma unroll
            for (int g = 0; g < 4; ++g)
                acc[g][l] += wv[g].x * pv.x + wv[g].y * pv.y + wv[g].z * pv.z + wv[g].w * pv.w;
        }
    }
#pragma unroll
    for (int g = 0; g < 4; ++g)
#pragma unroll
        for (int l = 0; l < 16; ++l) acc[g][l] = wave_sum(acc[g][l]);

    if (lane < 16) {
#pragma unroll
        for (int g = 0; g < 4; ++g)
            pooled[((size_t)b * L_ + lane) * C_ + cb + g] = acc[g][lane] + b1[b * C_ + cb + g];
    }
}

// ---------- pass 3b: out = pooled @ Wo^T + bo ----------
__global__ __launch_bounds__(256) void k_3b(const float* __restrict__ pooled,
                                            const float* __restrict__ Wo,
                                            const float* __restrict__ bo,
                                            float* __restrict__ out) {
    __shared__ __align__(16) float ps[4 * 768];
    const int t = threadIdx.x, w = t >> 6, lane = t & 63;
    const int rr0 = blockIdx.x * 4;

    for (int idx = t; idx < 4 * 768; idx += 256)
        ps[idx] = pooled[(size_t)rr0 * 768 + idx];
    __syncthreads();

    for (int d = w; d < 768; d += 4) {
        float a0 = 0.f, a1 = 0.f, a2 = 0.f, a3 = 0.f;
#pragma unroll
        for (int i = 0; i < 3; ++i) {
            int c = i * 256 + lane * 4;
            float4 wv = *reinterpret_cast<const float4*>(Wo + (size_t)d * 768 + c);
            float4 p0 = *reinterpret_cast<const float4*>(&ps[0 * 768 + c]);
            float4 p1 = *reinterpret_cast<const float4*>(&ps[1 * 768 + c]);
            float4 p2 = *reinterpret_cast<const float4*>(&ps[2 * 768 + c]);
            float4 p3 = *reinterpret_cast<const float4*>(&ps[3 * 768 + c]);
            a0 += wv.x * p0.x + wv.y * p0.y + wv.z * p0.z + wv.w * p0.w;
            a1 += wv.x * p1.x + wv.y * p1.y + wv.z * p1.z + wv.w * p1.w;
            a2 += wv.x * p2.x + wv.y * p2.y + wv.z * p2.z + wv.w * p2.w;
            a3 += wv.x * p3.x + wv.y * p3.y + wv.z * p3.z + wv.w * p3.w;
        }
        a0 = wave_sum(a0); a1 = wave_sum(a1); a2 = wave_sum(a2); a3 = wave_sum(a3);
        if (lane == 0) {
            float bb = bo[d];
            out[(size_t)(rr0 + 0) * 768 + d] = a0 + bb;
            out[(size_t)(rr0 + 1) * 768 + d] = a1 + bb;
            out[(size_t)(rr0 + 2) * 768 + d] = a2 + bb;
            out[(size_t)(rr0 + 3) * 768 + d] = a3 + bb;
        }
    }
}

extern "C" void kernel_launch(void* const* d_in, const int* in_sizes, int n_in,
                              void* d_out, int out_size, void* d_ws, size_t ws_size,
                              hipStream_t stream) {
    const float* x  = (const float*)d_in[0];
    const float* Wq = (const float*)d_in[1];
    const float* bq = (const float*)d_in[2];
    const float* W0 = (const float*)d_in[3];
    const float* b0 = (const float*)d_in[4];
    const float* W1 = (const float*)d_in[5];
    const float* b1 = (const float*)d_in[6];
    const float* Wo = (const float*)d_in[7];
    const float* bo = (const float*)d_in[8];
    float* out = (float*)d_out;

    char* p = (char*)d_ws;
    size_t off = 0;
    auto carve = [&](size_t bytes) -> char* {
        char* r = p + off;
        off += (bytes + 255) & ~(size_t)255;
        return r;
    };
    float* ph     = (float*)carve((size_t)B_ * L_ * H_ * 4); // 3.1 MB
    float* pooled = (float*)carve((size_t)B_ * L_ * C_ * 4); // 1.6 MB

    const size_t xb_bytes  = (size_t)B_ * T_ * C_ * 2;       // 100.7 MB
    const size_t w0b_bytes = (size_t)B_ * H_ * C_ * 2;       // 75.5 MB (Wfb)
    const size_t wq_bytes  = (size_t)C_ * C_ * 2;            // 1.2 MB
    const size_t b0f_bytes = (size_t)B_ * H_ * 4;            // 0.2 MB

    const int n4x  = B_ * T_ * C_ / 4;
    const int n4wq = C_ * C_ / 4;
    const int n4w0 = B_ * H_ * C_ / 4;

    // fast path peak: ph+pooled + b0f + WqTb + Wfb + xb ≈ 182 MB (no W0b at all)
    if (off + b0f_bytes + wq_bytes + w0b_bytes + xb_bytes + 1024 <= ws_size) {
        float* b0f  = (float*)carve(b0f_bytes);
        u16*   WqTb = (u16*)carve(wq_bytes);
        u16*   Wfb  = (u16*)carve(w0b_bytes);
        u16*   xb   = (u16*)carve(xb_bytes);

        // 1) x->bf16 | b0f = b0 + W0@bq (fp32 read; warms L3 with W0) | Wq^T->bf16
        k_prep_all<<<dim3(4096), 256, 0, stream>>>(x, xb, n4x, Wq, WqTb, W0,
                                                   bq, b0, b0f, 2704, 4060);
        // 2) Wf = W0(fp32) @ Wq  — W0 staged with in-kernel cvt (L3-warm)
        k_wf3<<<dim3(C_ / 128, (B_ * H_) / 128), 256, 0, stream>>>(W0, WqTb, Wfb);
        // 3) h = silu(x @ Wf^T + b0f), fused window-mean -> ph
        k_gemm9<1><<<dim3(H_ / 256, T_ / 256, B_), 512, 0, stream>>>(xb, Wfb, b0f, nullptr, ph);
    } else {
        // mid path (R8-proven): q = x@Wq^T via gemm9<0>, then gemm9<1>
        u16* qb  = (u16*)carve(xb_bytes);
        u16* Wqb = (u16*)carve(wq_bytes);
        u16* xb  = (u16*)carve(xb_bytes);
        u16* W0b = xb;   // alias: W0 converts after gemm9<0> consumed xb
        k_cvt<<<dim3(64), 256, 0, stream>>>(Wq, Wqb, n4wq);
        k_cvt<<<dim3(2048), 256, 0, stream>>>(x, xb, n4x);
        k_gemm9<0><<<dim3(C_ / 256, (B_ * T_) / 256), 512, 0, stream>>>(xb, Wqb, bq, qb, nullptr);
        k_cvt<<<dim3(2048), 256, 0, stream>>>(W0, W0b, n4w0);
        k_gemm9<1><<<dim3(H_ / 256, T_ / 256, B_), 512, 0, stream>>>(qb, W0b, b0, nullptr, ph);
    }

    k_3a<<<dim3(C_ / 16, B_), 256, 0, stream>>>(ph, W1, b1, pooled);
    k_3b<<<dim3(B_ * L_ / 4), 256, 0, stream>>>(pooled, Wo, bo, out);
}

// Round 13
// 678.782 us; speedup vs baseline: 1.0365x; 1.0365x over previous
//
#include <hip/hip_runtime.h>
#include <stdint.h>

#define B_ 32
#define T_ 2048
#define C_ 768
#define H_ 1536
#define L_ 16

typedef unsigned short u16;
typedef __bf16 bf16x8 __attribute__((ext_vector_type(8)));
typedef float f32x4 __attribute__((ext_vector_type(4)));

__device__ __forceinline__ u16 f2bf(float f) {
    union { float f; uint32_t u; } v; v.f = f;
    uint32_t r = (v.u + 0x7fffu + ((v.u >> 16) & 1u)) >> 16;
    return (u16)r;
}

__device__ __forceinline__ float wave_sum(float v) {
    v += __shfl_xor(v, 1);  v += __shfl_xor(v, 2);  v += __shfl_xor(v, 4);
    v += __shfl_xor(v, 8);  v += __shfl_xor(v, 16); v += __shfl_xor(v, 32);
    return v;
}

__global__ void k_cvt(const float* __restrict__ in, u16* __restrict__ out, int n4) {
    int stride = gridDim.x * blockDim.x;
    for (int i = blockIdx.x * blockDim.x + threadIdx.x; i < n4; i += stride) {
        float4 v = reinterpret_cast<const float4*>(in)[i];
        ushort4 o;
        o.x = f2bf(v.x); o.y = f2bf(v.y); o.z = f2bf(v.z); o.w = f2bf(v.w);
        reinterpret_cast<ushort4*>(out)[i] = o;
    }
}

// prep1: W0->bf16 (PURE stream, no dot) | Wq->bf16 TRANSPOSED
__global__ void k_prep1(const float* __restrict__ Wq, u16* __restrict__ WqTb,
                        const float* __restrict__ W0, u16* __restrict__ W0b,
                        int n4w0, int e0) {
    const int t = threadIdx.x;
    if (blockIdx.x < (unsigned)e0) {
        int stride = e0 * 256;
        for (int i = blockIdx.x * 256 + t; i < n4w0; i += stride) {
            float4 v = reinterpret_cast<const float4*>(W0)[i];
            ushort4 o;
            o.x = f2bf(v.x); o.y = f2bf(v.y); o.z = f2bf(v.z); o.w = f2bf(v.w);
            reinterpret_cast<ushort4*>(W0b)[i] = o;
        }
    } else {
        __shared__ u16 tl[64 * 65];
        const int nb = gridDim.x - e0;
        for (int tile = blockIdx.x - e0; tile < 144; tile += nb) {
            int d0 = (tile / 12) * 64, c0 = (tile % 12) * 64;
            __syncthreads();
#pragma unroll
            for (int p = 0; p < 16; ++p) {
                int idx = p * 256 + t;
                int r = idx >> 6, c = idx & 63;
                tl[r * 65 + c] = f2bf(Wq[(size_t)(d0 + r) * 768 + c0 + c]);
            }
            __syncthreads();
#pragma unroll
            for (int p = 0; p < 16; ++p) {
                int idx = p * 256 + t;
                int r = idx >> 6, c = idx & 63;
                WqTb[(size_t)(c0 + r) * 768 + d0 + c] = tl[c * 65 + r];
            }
        }
    }
}

__device__ __forceinline__ void gload16(const u16* g, u16* l) {
    __builtin_amdgcn_global_load_lds((const __attribute__((address_space(1))) void*)g,
                                     (__attribute__((address_space(3))) void*)l, 16, 0, 0);
}

// ==== 256x256 bf16 GEMM core (R8-proven: 1 barrier/K-tile, A 3-buf / B 2-buf) ====
template <int EPI>
__global__ __launch_bounds__(512, 2) void k_gemm9(const u16* __restrict__ Aall,
                                                  const u16* __restrict__ Ball,
                                                  const float* __restrict__ biasall,
                                                  u16* __restrict__ qout,
                                                  float* __restrict__ ph) {
    __shared__ u16 sm[81920];
    const int t = threadIdx.x;
    const int w = t >> 6, lane = t & 63;
    const int wr = w >> 2, wc = w & 3;
    const int l15 = lane & 15, kq = lane >> 4, cx = lane & 7;

    const int gx = gridDim.x, gy = gridDim.y;
    const int nwg = gx * gy * gridDim.z;
    int flat = blockIdx.x + gx * (blockIdx.y + gy * blockIdx.z);
    if ((nwg & 7) == 0) flat = (flat & 7) * (nwg >> 3) + (flat >> 3);
    const int bx = flat % gx;
    const int tmp = flat / gx;
    const int by = tmp % gy;
    const int bz = tmp / gy;

    const int n0 = bx * 256;
    const int m0 = by * 256;
    const u16* A; const u16* Bm; const float* bias;
    if constexpr (EPI == 0) {
        A = Aall + (size_t)m0 * C_;
        Bm = Ball + (size_t)n0 * C_;
        bias = biasall + n0;
    } else {
        A = Aall + ((size_t)bz * T_ + m0) * C_;
        Bm = Ball + ((size_t)bz * H_ + n0) * C_;
        bias = biasall + (size_t)bz * H_ + n0;
    }

    const int rl = (w << 4) + (lane >> 3);
    const int cs = (((lane & 7) ^ ((lane >> 3) & 7)) << 3);
    const int ldst = (w << 10);

    auto stA = [&](int kt, int buf) {
#pragma unroll
        for (int h = 0; h < 2; ++h) {
            const u16* g = A + (size_t)(h * 128 + rl) * C_ + kt * 64 + cs;
            u16* l = sm + buf * 16384 + h * 8192 + ldst;
            gload16(g, l);
            gload16(g + 8 * C_, l + 512);
        }
    };
    auto stB = [&](int kt, int buf) {
#pragma unroll
        for (int h = 0; h < 2; ++h) {
            const u16* g = Bm + (size_t)(h * 128 + rl) * C_ + kt * 64 + cs;
            u16* l = sm + 49152 + buf * 16384 + h * 8192 + ldst;
            gload16(g, l);
            gload16(g + 8 * C_, l + 512);
        }
    };

    f32x4 acc[8][4];
#pragma unroll
    for (int m = 0; m < 8; ++m)
#pragma unroll
        for (int n = 0; n < 4; ++n) acc[m][n] = (f32x4){0.f, 0.f, 0.f, 0.f};

    bf16x8 a0[4][2], a1[4][2], bfr[2][2];

    const int koff0 = ((kq ^ cx) << 3);
    const int koff1 = (((4 + kq) ^ cx) << 3);
    const u16* aB0 = sm + wr * 8192 + l15 * 64 + koff0;
    const u16* aB1 = sm + wr * 8192 + l15 * 64 + koff1;
    const u16* bB0 = sm + 49152 + (wc >> 1) * 8192 + (wc & 1) * 4096 + l15 * 64 + koff0;
    const u16* bB1 = sm + 49152 + (wc >> 1) * 8192 + (wc & 1) * 4096 + l15 * 64 + koff1;

    auto rdB0 = [&](int off) {
        bfr[0][0] = *reinterpret_cast<const bf16x8*>(bB0 + off);
        bfr[1][0] = *reinterpret_cast<const bf16x8*>(bB0 + off + 1024);
        bfr[0][1] = *reinterpret_cast<const bf16x8*>(bB1 + off);
        bfr[1][1] = *reinterpret_cast<const bf16x8*>(bB1 + off + 1024);
    };
    auto rdB1 = [&](int off) {
        bfr[0][0] = *reinterpret_cast<const bf16x8*>(bB0 + off + 2048);
        bfr[1][0] = *reinterpret_cast<const bf16x8*>(bB0 + off + 3072);
        bfr[0][1] = *reinterpret_cast<const bf16x8*>(bB1 + off + 2048);
        bfr[1][1] = *reinterpret_cast<const bf16x8*>(bB1 + off + 3072);
    };
    auto rdA0 = [&](int off) {
#pragma unroll
        for (int mm = 0; mm < 4; ++mm) {
            a0[mm][0] = *reinterpret_cast<const bf16x8*>(aB0 + off + mm * 1024);
            a0[mm][1] = *reinterpret_cast<const bf16x8*>(aB1 + off + mm * 1024);
        }
    };
    auto rdA1 = [&](int off) {
#pragma unroll
        for (int mm = 0; mm < 4; ++mm) {
            a1[mm][0] = *reinterpret_cast<const bf16x8*>(aB0 + off + 4096 + mm * 1024);
            a1[mm][1] = *reinterpret_cast<const bf16x8*>(aB1 + off + 4096 + mm * 1024);
        }
    };
    auto mma16 = [&](bf16x8 (&a)[4][2], int mq, int qn) {
        __builtin_amdgcn_s_setprio(1);
#pragma unroll
        for (int ks = 0; ks < 2; ++ks)
#pragma unroll
            for (int mm = 0; mm < 4; ++mm)
#pragma unroll
                for (int nn = 0; nn < 2; ++nn)
                    acc[mq * 4 + mm][qn * 2 + nn] = __builtin_amdgcn_mfma_f32_16x16x32_bf16(
                        a[mm][ks], bfr[nn][ks], acc[mq * 4 + mm][qn * 2 + nn], 0, 0, 0);
        __builtin_amdgcn_s_setprio(0);
    };

    stA(0, 0); stB(0, 0); stA(1, 1);
    asm volatile("s_waitcnt vmcnt(4)" ::: "memory");
    __builtin_amdgcn_s_barrier();

    int ba = 0;
#pragma unroll 1
    for (int kt = 0; kt < 12; ++kt) {
        const int bb = kt & 1;
        int ban = ba + 2; if (ban >= 3) ban -= 3;
        const bool s2 = (kt + 2 < 12);
        if (kt + 1 < 12) stB(kt + 1, bb ^ 1);
        if (s2) stA(kt + 2, ban);
        const int aoff = ba * 16384;
        const int boff = bb * 16384;
        rdB0(boff);
        rdA0(aoff);
        rdA1(aoff);
        mma16(a0, 0, 0);
        mma16(a1, 1, 0);
        __builtin_amdgcn_sched_barrier(0);
        rdB1(boff);
        mma16(a0, 0, 1);
        mma16(a1, 1, 1);
        if (s2) asm volatile("s_waitcnt vmcnt(4)" ::: "memory");
        else    asm volatile("s_waitcnt vmcnt(0)" ::: "memory");
        __builtin_amdgcn_s_barrier();
        ba = (ba + 1 == 3) ? 0 : ba + 1;
    }

    if constexpr (EPI == 0) {
        const int colb = n0 + wc * 64 + l15;
        const int rowb = m0 + wr * 128 + (kq << 2);
        float bv[4];
#pragma unroll
        for (int n = 0; n < 4; ++n) bv[n] = bias[wc * 64 + n * 16 + l15];
#pragma unroll
        for (int m = 0; m < 8; ++m)
#pragma unroll
            for (int r = 0; r < 4; ++r) {
                size_t ro = (size_t)(rowb + m * 16 + r) * C_;
#pragma unroll
                for (int n = 0; n < 4; ++n)
                    qout[ro + colb + n * 16] = f2bf(acc[m][n][r] + bv[n]);
            }
    } else {
        const int lwin = by * 2 + wr;
#pragma unroll
        for (int n = 0; n < 4; ++n) {
            int cloc = wc * 64 + n * 16 + l15;
            float bv = bias[cloc];
            float s = 0.f;
#pragma unroll
            for (int m = 0; m < 8; ++m)
#pragma unroll
                for (int r = 0; r < 4; ++r) {
                    float v = acc[m][n][r] + bv;
                    s += v / (1.f + __expf(-v));
                }
            s += __shfl_xor(s, 16);
            s += __shfl_xor(s, 32);
            if (kq == 0)
                ph[((size_t)bz * L_ + lwin) * H_ + n0 + cloc] = s * (1.f / 128.f);
        }
    }
}

__device__ __forceinline__ void stage_bf16_gload(const u16* gtile, int ld, u16* Ts,
                                                 int w, int lane) {
    const int r_in = lane >> 3;
    const int c0   = (lane & 7) << 3;
#pragma unroll
    for (int j = 0; j < 4; ++j) {
        int row = ((w << 2) + j) * 8 + r_in;
        const u16* g = gtile + (size_t)row * ld + c0;
        u16* l = Ts + (((w << 2) + j) << 9);
        gload16(g, l);
    }
}

__device__ __forceinline__ void stage_f32_cvt(const float* gtile, int ld, u16* Ts, int t) {
#pragma unroll
    for (int i = 0; i < 8; ++i) {
        int slot = t + (i << 8);
        int row  = slot >> 4;
        int c4   = (slot & 15) << 2;
        float4 v = *reinterpret_cast<const float4*>(gtile + (size_t)row * ld + c4);
        ushort4 o;
        o.x = f2bf(v.x); o.y = f2bf(v.y); o.z = f2bf(v.z); o.w = f2bf(v.w);
        *reinterpret_cast<ushort4*>(&Ts[row * 64 + c4]) = o;
    }
}

__device__ __forceinline__ void mfma_tile(const u16* As, const u16* Bs,
                                          f32x4 (&acc)[4][4], int wr, int wc, int lane) {
#pragma unroll
    for (int ks = 0; ks < 2; ++ks) {
        const int ko = (ks << 5) + ((lane >> 4) << 3);
        bf16x8 a[4], b[4];
#pragma unroll
        for (int m = 0; m < 4; ++m)
            a[m] = *reinterpret_cast<const bf16x8*>(&As[(wr * 64 + m * 16 + (lane & 15)) * 64 + ko]);
#pragma unroll
        for (int n = 0; n < 4; ++n)
            b[n] = *reinterpret_cast<const bf16x8*>(&Bs[(wc * 64 + n * 16 + (lane & 15)) * 64 + ko]);
#pragma unroll
        for (int m = 0; m < 4; ++m)
#pragma unroll
            for (int n = 0; n < 4; ++n)
                acc[m][n] = __builtin_amdgcn_mfma_f32_16x16x32_bf16(a[m], b[n], acc[m][n], 0, 0, 0);
    }
}

// ==== k_wf2: Wf = W0flat @ Wq (128^2 tiles) + fused b0f on bx==0 blocks ====
__global__ __launch_bounds__(256, 2) void k_wf2(const u16* __restrict__ W0b,
                                                const u16* __restrict__ WqTb,
                                                u16* __restrict__ Wfb,
                                                const float* __restrict__ bq,
                                                const float* __restrict__ b0,
                                                float* __restrict__ b0f) {
    __shared__ u16 smw[128 * 136];
    u16* As = smw;
    u16* Bs = smw + 8192;
    const int t = threadIdx.x, w = t >> 6, lane = t & 63;
    const int wr = w >> 1, wc = w & 1;
    const int m0 = blockIdx.y * 128;
    const int n0 = blockIdx.x * 128;
    const bool doDot = (blockIdx.x == 0);
    const int drow = w * 32 + (lane >> 1);        // this lane's b0f row (local)
    const int dk0 = (lane & 1) * 32;              // k-half within tile
    float dot = 0.f;

    f32x4 acc[4][4];
#pragma unroll
    for (int m = 0; m < 4; ++m)
#pragma unroll
        for (int n = 0; n < 4; ++n) acc[m][n] = (f32x4){0.f, 0.f, 0.f, 0.f};

    for (int kt = 0; kt < 12; ++kt) {
        stage_bf16_gload(W0b + (size_t)m0 * C_ + kt * 64, C_, As, w, lane);
        stage_bf16_gload(WqTb + (size_t)n0 * C_ + kt * 64, C_, Bs, w, lane);
        __syncthreads();
        mfma_tile(As, Bs, acc, wr, wc, lane);
        if (doDot) {
            // dot(W0b[drow], bq) over this tile's 32-k half (linear As layout)
            const u16* ap = As + drow * 64 + dk0;
            const float* bp = bq + kt * 64 + dk0;
#pragma unroll
            for (int j8 = 0; j8 < 4; ++j8) {
                bf16x8 a8 = *reinterpret_cast<const bf16x8*>(ap + j8 * 8);
#pragma unroll
                for (int j = 0; j < 8; ++j)
                    dot += (float)a8[j] * bp[j8 * 8 + j];
            }
        }
        __syncthreads();
    }

    if (doDot) {
        dot += __shfl_xor(dot, 1);
        if (!(lane & 1)) {
            int rr = m0 + drow;
            b0f[rr] = b0[rr] + dot;
        }
    }

    // epilogue: acc -> LDS [128][136] -> coalesced 16B stores
    const int lr0 = wr * 64 + ((lane >> 4) << 2);
    const int lc0 = wc * 64 + (lane & 15);
#pragma unroll
    for (int m = 0; m < 4; ++m)
#pragma unroll
        for (int n = 0; n < 4; ++n)
#pragma unroll
            for (int r = 0; r < 4; ++r)
                smw[(lr0 + m * 16 + r) * 136 + lc0 + n * 16] = f2bf(acc[m][n][r]);
    __syncthreads();
    u16* G = Wfb + (size_t)m0 * C_ + n0;
#pragma unroll
    for (int p = 0; p < 8; ++p) {
        int fl = p * 256 + t;
        int row = fl >> 4, c8 = fl & 15;
        f32x4 v = *reinterpret_cast<const f32x4*>(&smw[row * 136 + c8 * 8]);
        *reinterpret_cast<f32x4*>(&G[(size_t)row * C_ + c8 * 8]) = v;
    }
}

// ---------- pass 3a: pooled = pooled_h @ W1[b]^T + b1 ----------
__global__ __launch_bounds__(256) void k_3a(const float* __restrict__ ph,
                                            const float* __restrict__ W1,
                                            const float* __restrict__ b1,
                                            float* __restrict__ pooled) {
    const int t = threadIdx.x, w = t >> 6, lane = t & 63;
    const int b  = blockIdx.y;
    const int cb = blockIdx.x * 16 + w * 4;

    float acc[4][16];
#pragma unroll
    for (int g = 0; g < 4; ++g)
#pragma unroll
        for (int l = 0; l < 16; ++l) acc[g][l] = 0.f;

    for (int i = 0; i < H_ / 256; ++i) {
        int h0 = i * 256 + lane * 4;
        float4 wv[4];
#pragma unroll
        for (int g = 0; g < 4; ++g)
            wv[g] = *reinterpret_cast<const float4*>(W1 + ((size_t)b * C_ + cb + g) * H_ + h0);
#pragma unroll
        for (int l = 0; l < 16; ++l) {
            float4 pv = *reinterpret_cast<const float4*>(ph + ((size_t)b * L_ + l) * H_ + h0);
#pragma unroll
            for (int g = 0; g < 4; ++g)
                acc[g][l] += wv[g].x * pv.x + wv[g].y * pv.y + wv[g].z * pv.z + wv[g].w * pv.w;
        }
    }
#pragma unroll
    for (int g = 0; g < 4; ++g)
#pragma unroll
        for (int l = 0; l < 16; ++l) acc[g][l] = wave_sum(acc[g][l]);

    if (lane < 16) {
#pragma unroll
        for (int g = 0; g < 4; ++g)
            pooled[((size_t)b * L_ + lane) * C_ + cb + g] = acc[g][lane] + b1[b * C_ + cb + g];
    }
}

// ---------- pass 3b: out = pooled @ Wo^T + bo ----------
__global__ __launch_bounds__(256) void k_3b(const float* __restrict__ pooled,
                                            const float* __restrict__ Wo,
                                            const float* __restrict__ bo,
                                            float* __restrict__ out) {
    __shared__ __align__(16) float ps[4 * 768];
    const int t = threadIdx.x, w = t >> 6, lane = t & 63;
    const int rr0 = blockIdx.x * 4;

    for (int idx = t; idx < 4 * 768; idx += 256)
        ps[idx] = pooled[(size_t)rr0 * 768 + idx];
    __syncthreads();

    for (int d = w; d < 768; d += 4) {
        float a0 = 0.f, a1 = 0.f, a2 = 0.f, a3 = 0.f;
#pragma unroll
        for (int i = 0; i < 3; ++i) {
            int c = i * 256 + lane * 4;
            float4 wv = *reinterpret_cast<const float4*>(Wo + (size_t)d * 768 + c);
            float4 p0 = *reinterpret_cast<const float4*>(&ps[0 * 768 + c]);
            float4 p1 = *reinterpret_cast<const float4*>(&ps[1 * 768 + c]);
            float4 p2 = *reinterpret_cast<const float4*>(&ps[2 * 768 + c]);
            float4 p3 = *reinterpret_cast<const float4*>(&ps[3 * 768 + c]);
            a0 += wv.x * p0.x + wv.y * p0.y + wv.z * p0.z + wv.w * p0.w;
            a1 += wv.x * p1.x + wv.y * p1.y + wv.z * p1.z + wv.w * p1.w;
            a2 += wv.x * p2.x + wv.y * p2.y + wv.z * p2.z + wv.w * p2.w;
            a3 += wv.x * p3.x + wv.y * p3.y + wv.z * p3.z + wv.w * p3.w;
        }
        a0 = wave_sum(a0); a1 = wave_sum(a1); a2 = wave_sum(a2); a3 = wave_sum(a3);
        if (lane == 0) {
            float bb = bo[d];
            out[(size_t)(rr0 + 0) * 768 + d] = a0 + bb;
            out[(size_t)(rr0 + 1) * 768 + d] = a1 + bb;
            out[(size_t)(rr0 + 2) * 768 + d] = a2 + bb;
            out[(size_t)(rr0 + 3) * 768 + d] = a3 + bb;
        }
    }
}

extern "C" void kernel_launch(void* const* d_in, const int* in_sizes, int n_in,
                              void* d_out, int out_size, void* d_ws, size_t ws_size,
                              hipStream_t stream) {
    const float* x  = (const float*)d_in[0];
    const float* Wq = (const float*)d_in[1];
    const float* bq = (const float*)d_in[2];
    const float* W0 = (const float*)d_in[3];
    const float* b0 = (const float*)d_in[4];
    const float* W1 = (const float*)d_in[5];
    const float* b1 = (const float*)d_in[6];
    const float* Wo = (const float*)d_in[7];
    const float* bo = (const float*)d_in[8];
    float* out = (float*)d_out;

    char* p = (char*)d_ws;
    size_t off = 0;
    auto carve = [&](size_t bytes) -> char* {
        char* r = p + off;
        off += (bytes + 255) & ~(size_t)255;
        return r;
    };
    float* ph     = (float*)carve((size_t)B_ * L_ * H_ * 4); // 3.1 MB
    float* pooled = (float*)carve((size_t)B_ * L_ * C_ * 4); // 1.6 MB

    const size_t xb_bytes  = (size_t)B_ * T_ * C_ * 2;       // 100.7 MB
    const size_t w0b_bytes = (size_t)B_ * H_ * C_ * 2;       // 75.5 MB
    const size_t wq_bytes  = (size_t)C_ * C_ * 2;            // 1.2 MB
    const size_t b0f_bytes = (size_t)B_ * H_ * 4;            // 0.2 MB

    const int n4x  = B_ * T_ * C_ / 4;
    const int n4wq = C_ * C_ / 4;
    const int n4w0 = B_ * H_ * C_ / 4;

    // fast path peak: ph+pooled + b0f + WqTb + Wfb + union(W0b, xb) ≈ 182 MB
    if (off + b0f_bytes + wq_bytes + w0b_bytes + xb_bytes + 1024 <= ws_size) {
        float* b0f  = (float*)carve(b0f_bytes);
        u16*   WqTb = (u16*)carve(wq_bytes);
        u16*   Wfb  = (u16*)carve(w0b_bytes);
        u16*   U    = (u16*)carve(xb_bytes);   // union region
        u16*   W0b  = U;                       // live: prep1 -> k_wf2
        u16*   xb   = U;                       // live: cvt -> gemm9 (overwrites W0b)

        // 1) W0->bf16 (pure stream) + Wq^T->bf16
        k_prep1<<<dim3(2048), 256, 0, stream>>>(Wq, WqTb, W0, W0b, n4w0, 2016);
        // 2) Wf = W0flat @ Wq; bx==0 blocks also compute b0f = b0 + W0@bq
        k_wf2<<<dim3(C_ / 128, (B_ * H_) / 128), 256, 0, stream>>>(W0b, WqTb, Wfb,
                                                                   bq, b0, b0f);
        // 3) x -> bf16 (into the region W0b occupied; W0b dead after k_wf2)
        k_cvt<<<dim3(2048), 256, 0, stream>>>(x, xb, n4x);
        // 4) h = silu(x @ Wf^T + b0f), fused window-mean -> ph
        k_gemm9<1><<<dim3(H_ / 256, T_ / 256, B_), 512, 0, stream>>>(xb, Wfb, b0f, nullptr, ph);
    } else {
        // mid path (R8-proven): q = x@Wq^T via gemm9<0>, then gemm9<1>
        u16* qb  = (u16*)carve(xb_bytes);
        u16* Wqb = (u16*)carve(wq_bytes);
        u16* xb  = (u16*)carve(xb_bytes);
        u16* W0b = xb;   // alias: W0 converts after gemm9<0> consumed xb
        k_cvt<<<dim3(64), 256, 0, stream>>>(Wq, Wqb, n4wq);
        k_cvt<<<dim3(2048), 256, 0, stream>>>(x, xb, n4x);
        k_gemm9<0><<<dim3(C_ / 256, (B_ * T_) / 256), 512, 0, stream>>>(xb, Wqb, bq, qb, nullptr);
        k_cvt<<<dim3(2048), 256, 0, stream>>>(W0, W0b, n4w0);
        k_gemm9<1><<<dim3(H_ / 256, T_ / 256, B_), 512, 0, stream>>>(qb, W0b, b0, nullptr, ph);
    }

    k_3a<<<dim3(C_ / 16, B_), 256, 0, stream>>>(ph, W1, b1, pooled);
    k_3b<<<dim3(B_ * L_ / 4), 256, 0, stream>>>(pooled, Wo, bo, out);
}

// Round 14
// 616.000 us; speedup vs baseline: 1.1422x; 1.1019x over previous
//
#include <hip/hip_runtime.h>
#include <stdint.h>

#define B_ 32
#define T_ 2048
#define C_ 768
#define H_ 1536
#define L_ 16

typedef unsigned short u16;
typedef __bf16 bf16x8 __attribute__((ext_vector_type(8)));
typedef float f32x4 __attribute__((ext_vector_type(4)));

__device__ __forceinline__ u16 f2bf(float f) {
    union { float f; uint32_t u; } v; v.f = f;
    uint32_t r = (v.u + 0x7fffu + ((v.u >> 16) & 1u)) >> 16;
    return (u16)r;
}

__device__ __forceinline__ float wave_sum(float v) {
    v += __shfl_xor(v, 1);  v += __shfl_xor(v, 2);  v += __shfl_xor(v, 4);
    v += __shfl_xor(v, 8);  v += __shfl_xor(v, 16); v += __shfl_xor(v, 32);
    return v;
}

__global__ void k_cvt(const float* __restrict__ in, u16* __restrict__ out, int n4) {
    int stride = gridDim.x * blockDim.x;
    for (int i = blockIdx.x * blockDim.x + threadIdx.x; i < n4; i += stride) {
        float4 v = reinterpret_cast<const float4*>(in)[i];
        ushort4 o;
        o.x = f2bf(v.x); o.y = f2bf(v.y); o.z = f2bf(v.z); o.w = f2bf(v.w);
        reinterpret_cast<ushort4*>(out)[i] = o;
    }
}

// prep1: W0->bf16 + b0f = b0 + W0@bq (fp32, exact) | Wq->bf16 TRANSPOSED
__global__ void k_prep1(const float* __restrict__ Wq, u16* __restrict__ WqTb,
                        const float* __restrict__ W0, u16* __restrict__ W0b,
                        const float* __restrict__ bq, const float* __restrict__ b0,
                        float* __restrict__ b0f, int e0) {
    const int t = threadIdx.x;
    if (blockIdx.x < (unsigned)e0) {
        const int w = t >> 6, lane = t & 63;
        const int nWaves = e0 * 4;
        const float4* bq4 = reinterpret_cast<const float4*>(bq);
        float4 b4_0 = bq4[lane], b4_1 = bq4[64 + lane], b4_2 = bq4[128 + lane];
        for (int rr = blockIdx.x * 4 + w; rr < B_ * H_; rr += nWaves) {
            const float4* src = reinterpret_cast<const float4*>(W0 + (size_t)rr * 768);
            ushort4* dst = reinterpret_cast<ushort4*>(W0b + (size_t)rr * 768);
            float4 v0 = src[lane], v1 = src[64 + lane], v2 = src[128 + lane];
            ushort4 o0, o1, o2;
            o0.x = f2bf(v0.x); o0.y = f2bf(v0.y); o0.z = f2bf(v0.z); o0.w = f2bf(v0.w);
            o1.x = f2bf(v1.x); o1.y = f2bf(v1.y); o1.z = f2bf(v1.z); o1.w = f2bf(v1.w);
            o2.x = f2bf(v2.x); o2.y = f2bf(v2.y); o2.z = f2bf(v2.z); o2.w = f2bf(v2.w);
            dst[lane] = o0; dst[64 + lane] = o1; dst[128 + lane] = o2;
            float dot = v0.x * b4_0.x + v0.y * b4_0.y + v0.z * b4_0.z + v0.w * b4_0.w
                      + v1.x * b4_1.x + v1.y * b4_1.y + v1.z * b4_1.z + v1.w * b4_1.w
                      + v2.x * b4_2.x + v2.y * b4_2.y + v2.z * b4_2.z + v2.w * b4_2.w;
            dot = wave_sum(dot);
            if (lane == 0) b0f[rr] = b0[rr] + dot;
        }
    } else {
        __shared__ u16 tl[64 * 65];
        const int nb = gridDim.x - e0;
        for (int tile = blockIdx.x - e0; tile < 144; tile += nb) {
            int d0 = (tile / 12) * 64, c0 = (tile % 12) * 64;
            __syncthreads();
#pragma unroll
            for (int p = 0; p < 16; ++p) {
                int idx = p * 256 + t;
                int r = idx >> 6, c = idx & 63;
                tl[r * 65 + c] = f2bf(Wq[(size_t)(d0 + r) * 768 + c0 + c]);
            }
            __syncthreads();
#pragma unroll
            for (int p = 0; p < 16; ++p) {
                int idx = p * 256 + t;
                int r = idx >> 6, c = idx & 63;
                WqTb[(size_t)(c0 + r) * 768 + d0 + c] = tl[c * 65 + r];
            }
        }
    }
}

__device__ __forceinline__ void gload16(const u16* g, u16* l) {
    __builtin_amdgcn_global_load_lds((const __attribute__((address_space(1))) void*)g,
                                     (__attribute__((address_space(3))) void*)l, 16, 0, 0);
}

// ==== 256x256 bf16 GEMM core (R8-proven: 1 barrier/K-tile, A 3-buf / B 2-buf) ====
// EPI 1: silu + window-mean -> ph.  EPI 0: bf16 store (mid-path fallback).
template <int EPI>
__global__ __launch_bounds__(512, 2) void k_gemm9(const u16* __restrict__ Aall,
                                                  const u16* __restrict__ Ball,
                                                  const float* __restrict__ biasall,
                                                  u16* __restrict__ qout,
                                                  float* __restrict__ ph) {
    __shared__ u16 sm[81920];
    const int t = threadIdx.x;
    const int w = t >> 6, lane = t & 63;
    const int wr = w >> 2, wc = w & 3;
    const int l15 = lane & 15, kq = lane >> 4, cx = lane & 7;

    const int gx = gridDim.x, gy = gridDim.y;
    const int nwg = gx * gy * gridDim.z;
    int flat = blockIdx.x + gx * (blockIdx.y + gy * blockIdx.z);
    if ((nwg & 7) == 0) flat = (flat & 7) * (nwg >> 3) + (flat >> 3);
    const int bx = flat % gx;
    const int tmp = flat / gx;
    const int by = tmp % gy;
    const int bz = tmp / gy;

    const int n0 = bx * 256;
    const int m0 = by * 256;
    const u16* A; const u16* Bm; const float* bias;
    if constexpr (EPI == 0) {
        A = Aall + (size_t)m0 * C_;
        Bm = Ball + (size_t)n0 * C_;
        bias = biasall + n0;
    } else {
        A = Aall + ((size_t)bz * T_ + m0) * C_;
        Bm = Ball + ((size_t)bz * H_ + n0) * C_;
        bias = biasall + (size_t)bz * H_ + n0;
    }

    const int rl = (w << 4) + (lane >> 3);
    const int cs = (((lane & 7) ^ ((lane >> 3) & 7)) << 3);
    const int ldst = (w << 10);

    auto stA = [&](int kt, int buf) {
#pragma unroll
        for (int h = 0; h < 2; ++h) {
            const u16* g = A + (size_t)(h * 128 + rl) * C_ + kt * 64 + cs;
            u16* l = sm + buf * 16384 + h * 8192 + ldst;
            gload16(g, l);
            gload16(g + 8 * C_, l + 512);
        }
    };
    auto stB = [&](int kt, int buf) {
#pragma unroll
        for (int h = 0; h < 2; ++h) {
            const u16* g = Bm + (size_t)(h * 128 + rl) * C_ + kt * 64 + cs;
            u16* l = sm + 49152 + buf * 16384 + h * 8192 + ldst;
            gload16(g, l);
            gload16(g + 8 * C_, l + 512);
        }
    };

    f32x4 acc[8][4];
#pragma unroll
    for (int m = 0; m < 8; ++m)
#pragma unroll
        for (int n = 0; n < 4; ++n) acc[m][n] = (f32x4){0.f, 0.f, 0.f, 0.f};

    bf16x8 a0[4][2], a1[4][2], bfr[2][2];

    const int koff0 = ((kq ^ cx) << 3);
    const int koff1 = (((4 + kq) ^ cx) << 3);
    const u16* aB0 = sm + wr * 8192 + l15 * 64 + koff0;
    const u16* aB1 = sm + wr * 8192 + l15 * 64 + koff1;
    const u16* bB0 = sm + 49152 + (wc >> 1) * 8192 + (wc & 1) * 4096 + l15 * 64 + koff0;
    const u16* bB1 = sm + 49152 + (wc >> 1) * 8192 + (wc & 1) * 4096 + l15 * 64 + koff1;

    auto rdB0 = [&](int off) {
        bfr[0][0] = *reinterpret_cast<const bf16x8*>(bB0 + off);
        bfr[1][0] = *reinterpret_cast<const bf16x8*>(bB0 + off + 1024);
        bfr[0][1] = *reinterpret_cast<const bf16x8*>(bB1 + off);
        bfr[1][1] = *reinterpret_cast<const bf16x8*>(bB1 + off + 1024);
    };
    auto rdB1 = [&](int off) {
        bfr[0][0] = *reinterpret_cast<const bf16x8*>(bB0 + off + 2048);
        bfr[1][0] = *reinterpret_cast<const bf16x8*>(bB0 + off + 3072);
        bfr[0][1] = *reinterpret_cast<const bf16x8*>(bB1 + off + 2048);
        bfr[1][1] = *reinterpret_cast<const bf16x8*>(bB1 + off + 3072);
    };
    auto rdA0 = [&](int off) {
#pragma unroll
        for (int mm = 0; mm < 4; ++mm) {
            a0[mm][0] = *reinterpret_cast<const bf16x8*>(aB0 + off + mm * 1024);
            a0[mm][1] = *reinterpret_cast<const bf16x8*>(aB1 + off + mm * 1024);
        }
    };
    auto rdA1 = [&](int off) {
#pragma unroll
        for (int mm = 0; mm < 4; ++mm) {
            a1[mm][0] = *reinterpret_cast<const bf16x8*>(aB0 + off + 4096 + mm * 1024);
            a1[mm][1] = *reinterpret_cast<const bf16x8*>(aB1 + off + 4096 + mm * 1024);
        }
    };
    auto mma16 = [&](bf16x8 (&a)[4][2], int mq, int qn) {
        __builtin_amdgcn_s_setprio(1);
#pragma unroll
        for (int ks = 0; ks < 2; ++ks)
#pragma unroll
            for (int mm = 0; mm < 4; ++mm)
#pragma unroll
                for (int nn = 0; nn < 2; ++nn)
                    acc[mq * 4 + mm][qn * 2 + nn] = __builtin_amdgcn_mfma_f32_16x16x32_bf16(
                        a[mm][ks], bfr[nn][ks], acc[mq * 4 + mm][qn * 2 + nn], 0, 0, 0);
        __builtin_amdgcn_s_setprio(0);
    };

    stA(0, 0); stB(0, 0); stA(1, 1);
    asm volatile("s_waitcnt vmcnt(4)" ::: "memory");
    __builtin_amdgcn_s_barrier();

    int ba = 0;
#pragma unroll 1
    for (int kt = 0; kt < 12; ++kt) {
        const int bb = kt & 1;
        int ban = ba + 2; if (ban >= 3) ban -= 3;
        const bool s2 = (kt + 2 < 12);
        if (kt + 1 < 12) stB(kt + 1, bb ^ 1);
        if (s2) stA(kt + 2, ban);
        const int aoff = ba * 16384;
        const int boff = bb * 16384;
        rdB0(boff);
        rdA0(aoff);
        rdA1(aoff);
        mma16(a0, 0, 0);
        mma16(a1, 1, 0);
        __builtin_amdgcn_sched_barrier(0);
        rdB1(boff);
        mma16(a0, 0, 1);
        mma16(a1, 1, 1);
        if (s2) asm volatile("s_waitcnt vmcnt(4)" ::: "memory");
        else    asm volatile("s_waitcnt vmcnt(0)" ::: "memory");
        __builtin_amdgcn_s_barrier();
        ba = (ba + 1 == 3) ? 0 : ba + 1;
    }

    if constexpr (EPI == 0) {
        const int colb = n0 + wc * 64 + l15;
        const int rowb = m0 + wr * 128 + (kq << 2);
        float bv[4];
#pragma unroll
        for (int n = 0; n < 4; ++n) bv[n] = bias[wc * 64 + n * 16 + l15];
#pragma unroll
        for (int m = 0; m < 8; ++m)
#pragma unroll
            for (int r = 0; r < 4; ++r) {
                size_t ro = (size_t)(rowb + m * 16 + r) * C_;
#pragma unroll
                for (int n = 0; n < 4; ++n)
                    qout[ro + colb + n * 16] = f2bf(acc[m][n][r] + bv[n]);
            }
    } else {
        const int lwin = by * 2 + wr;
#pragma unroll
        for (int n = 0; n < 4; ++n) {
            int cloc = wc * 64 + n * 16 + l15;
            float bv = bias[cloc];
            float s = 0.f;
#pragma unroll
            for (int m = 0; m < 8; ++m)
#pragma unroll
                for (int r = 0; r < 4; ++r) {
                    float v = acc[m][n][r] + bv;
                    s += v / (1.f + __expf(-v));
                }
            s += __shfl_xor(s, 16);
            s += __shfl_xor(s, 32);
            if (kq == 0)
                ph[((size_t)bz * L_ + lwin) * H_ + n0 + cloc] = s * (1.f / 128.f);
        }
    }
}

// ==== k_wf: Wf[b] = W0[b] @ Wq (A=W0b [H,C], B=WqTb [C,C] K-major) -> bf16 ====
__global__ __launch_bounds__(512, 2) void k_wf(const u16* __restrict__ W0b,
                                               const u16* __restrict__ WqTb,
                                               u16* __restrict__ Wfb) {
    __shared__ u16 sm[81920];
    const int t = threadIdx.x;
    const int w = t >> 6, lane = t & 63;
    const int wr = w >> 2, wc = w & 3;
    const int l15 = lane & 15, kq = lane >> 4, cx = lane & 7;

    const int gx = gridDim.x, gy = gridDim.y;
    const int nwg = gx * gy * gridDim.z;
    int flat = blockIdx.x + gx * (blockIdx.y + gy * blockIdx.z);
    if ((nwg & 7) == 0) flat = (flat & 7) * (nwg >> 3) + (flat >> 3);
    const int bx = flat % gx;
    const int tmp = flat / gx;
    const int by = tmp % gy;
    const int bz = tmp / gy;

    const int n0 = bx * 256;           // c cols
    const int m0 = by * 256;           // h rows
    const u16* A = W0b + ((size_t)bz * H_ + m0) * C_;
    const u16* Bm = WqTb + (size_t)n0 * C_;

    const int rl = (w << 4) + (lane >> 3);
    const int cs = (((lane & 7) ^ ((lane >> 3) & 7)) << 3);
    const int ldst = (w << 10);

    auto stA = [&](int kt, int buf) {
#pragma unroll
        for (int h = 0; h < 2; ++h) {
            const u16* g = A + (size_t)(h * 128 + rl) * C_ + kt * 64 + cs;
            u16* l = sm + buf * 16384 + h * 8192 + ldst;
            gload16(g, l);
            gload16(g + 8 * C_, l + 512);
        }
    };
    auto stB = [&](int kt, int buf) {
#pragma unroll
        for (int h = 0; h < 2; ++h) {
            const u16* g = Bm + (size_t)(h * 128 + rl) * C_ + kt * 64 + cs;
            u16* l = sm + 49152 + buf * 16384 + h * 8192 + ldst;
            gload16(g, l);
            gload16(g + 8 * C_, l + 512);
        }
    };

    f32x4 acc[8][4];
#pragma unroll
    for (int m = 0; m < 8; ++m)
#pragma unroll
        for (int n = 0; n < 4; ++n) acc[m][n] = (f32x4){0.f, 0.f, 0.f, 0.f};

    bf16x8 a0[4][2], a1[4][2], bfr[2][2];

    const int koff0 = ((kq ^ cx) << 3);
    const int koff1 = (((4 + kq) ^ cx) << 3);
    const u16* aB0 = sm + wr * 8192 + l15 * 64 + koff0;
    const u16* aB1 = sm + wr * 8192 + l15 * 64 + koff1;
    const u16* bB0 = sm + 49152 + (wc >> 1) * 8192 + (wc & 1) * 4096 + l15 * 64 + koff0;
    const u16* bB1 = sm + 49152 + (wc >> 1) * 8192 + (wc & 1) * 4096 + l15 * 64 + koff1;

    auto rdB0 = [&](int off) {
        bfr[0][0] = *reinterpret_cast<const bf16x8*>(bB0 + off);
        bfr[1][0] = *reinterpret_cast<const bf16x8*>(bB0 + off + 1024);
        bfr[0][1] = *reinterpret_cast<const bf16x8*>(bB1 + off);
        bfr[1][1] = *reinterpret_cast<const bf16x8*>(bB1 + off + 1024);
    };
    auto rdB1 = [&](int off) {
        bfr[0][0] = *reinterpret_cast<const bf16x8*>(bB0 + off + 2048);
        bfr[1][0] = *reinterpret_cast<const bf16x8*>(bB0 + off + 3072);
        bfr[0][1] = *reinterpret_cast<const bf16x8*>(bB1 + off + 2048);
        bfr[1][1] = *reinterpret_cast<const bf16x8*>(bB1 + off + 3072);
    };
    auto rdA0 = [&](int off) {
#pragma unroll
        for (int mm = 0; mm < 4; ++mm) {
            a0[mm][0] = *reinterpret_cast<const bf16x8*>(aB0 + off + mm * 1024);
            a0[mm][1] = *reinterpret_cast<const bf16x8*>(aB1 + off + mm * 1024);
        }
    };
    auto rdA1 = [&](int off) {
#pragma unroll
        for (int mm = 0; mm < 4; ++mm) {
            a1[mm][0] = *reinterpret_cast<const bf16x8*>(aB0 + off + 4096 + mm * 1024);
            a1[mm][1] = *reinterpret_cast<const bf16x8*>(aB1 + off + 4096 + mm * 1024);
        }
    };
    auto mma16 = [&](bf16x8 (&a)[4][2], int mq, int qn) {
        __builtin_amdgcn_s_setprio(1);
#pragma unroll
        for (int ks = 0; ks < 2; ++ks)
#pragma unroll
            for (int mm = 0; mm < 4; ++mm)
#pragma unroll
                for (int nn = 0; nn < 2; ++nn)
                    acc[mq * 4 + mm][qn * 2 + nn] = __builtin_amdgcn_mfma_f32_16x16x32_bf16(
                        a[mm][ks], bfr[nn][ks], acc[mq * 4 + mm][qn * 2 + nn], 0, 0, 0);
        __builtin_amdgcn_s_setprio(0);
    };

    stA(0, 0); stB(0, 0); stA(1, 1);
    asm volatile("s_waitcnt vmcnt(4)" ::: "memory");
    __builtin_amdgcn_s_barrier();

    int ba = 0;
#pragma unroll 1
    for (int kt = 0; kt < 12; ++kt) {
        const int bb = kt & 1;
        int ban = ba + 2; if (ban >= 3) ban -= 3;
        const bool s2 = (kt + 2 < 12);
        if (kt + 1 < 12) stB(kt + 1, bb ^ 1);
        if (s2) stA(kt + 2, ban);
        const int aoff = ba * 16384;
        const int boff = bb * 16384;
        rdB0(boff);
        rdA0(aoff);
        rdA1(aoff);
        mma16(a0, 0, 0);
        mma16(a1, 1, 0);
        __builtin_amdgcn_sched_barrier(0);
        rdB1(boff);
        mma16(a0, 0, 1);
        mma16(a1, 1, 1);
        if (s2) asm volatile("s_waitcnt vmcnt(4)" ::: "memory");
        else    asm volatile("s_waitcnt vmcnt(0)" ::: "memory");
        __builtin_amdgcn_s_barrier();
        ba = (ba + 1 == 3) ? 0 : ba + 1;
    }

    // coalesced epilogue: acc -> LDS [256][264] u16 -> dwordx4 global stores
    const int lr0 = wr * 128 + (kq << 2);
    const int lc0 = wc * 64 + l15;
#pragma unroll
    for (int m = 0; m < 8; ++m)
#pragma unroll
        for (int n = 0; n < 4; ++n)
#pragma unroll
            for (int r = 0; r < 4; ++r)
                sm[(lr0 + m * 16 + r) * 264 + lc0 + n * 16] = f2bf(acc[m][n][r]);
    __builtin_amdgcn_s_barrier();
    u16* G = Wfb + ((size_t)bz * H_ + m0) * C_ + n0;
#pragma unroll
    for (int p = 0; p < 16; ++p) {
        int fl = p * 512 + t;
        int row = fl >> 5, c8 = fl & 31;
        f32x4 v = *reinterpret_cast<const f32x4*>(&sm[row * 264 + c8 * 8]);
        *reinterpret_cast<f32x4*>(&G[(size_t)row * C_ + c8 * 8]) = v;
    }
}

// ---------- pass 3a: pooled = pooled_h @ W1[b]^T + b1 ----------
__global__ __launch_bounds__(256) void k_3a(const float* __restrict__ ph,
                                            const float* __restrict__ W1,
                                            const float* __restrict__ b1,
                                            float* __restrict__ pooled) {
    const int t = threadIdx.x, w = t >> 6, lane = t & 63;
    const int b  = blockIdx.y;
    const int cb = blockIdx.x * 16 + w * 4;

    float acc[4][16];
#pragma unroll
    for (int g = 0; g < 4; ++g)
#pragma unroll
        for (int l = 0; l < 16; ++l) acc[g][l] = 0.f;

    for (int i = 0; i < H_ / 256; ++i) {
        int h0 = i * 256 + lane * 4;
        float4 wv[4];
#pragma unroll
        for (int g = 0; g < 4; ++g)
            wv[g] = *reinterpret_cast<const float4*>(W1 + ((size_t)b * C_ + cb + g) * H_ + h0);
#pragma unroll
        for (int l = 0; l < 16; ++l) {
            float4 pv = *reinterpret_cast<const float4*>(ph + ((size_t)b * L_ + l) * H_ + h0);
#pragma unroll
            for (int g = 0; g < 4; ++g)
                acc[g][l] += wv[g].x * pv.x + wv[g].y * pv.y + wv[g].z * pv.z + wv[g].w * pv.w;
        }
    }
#pragma unroll
    for (int g = 0; g < 4; ++g)
#pragma unroll
        for (int l = 0; l < 16; ++l) acc[g][l] = wave_sum(acc[g][l]);

    if (lane < 16) {
#pragma unroll
        for (int g = 0; g < 4; ++g)
            pooled[((size_t)b * L_ + lane) * C_ + cb + g] = acc[g][lane] + b1[b * C_ + cb + g];
    }
}

// ---------- pass 3b: out = pooled @ Wo^T + bo ----------
__global__ __launch_bounds__(256) void k_3b(const float* __restrict__ pooled,
                                            const float* __restrict__ Wo,
                                            const float* __restrict__ bo,
                                            float* __restrict__ out) {
    __shared__ __align__(16) float ps[4 * 768];
    const int t = threadIdx.x, w = t >> 6, lane = t & 63;
    const int rr0 = blockIdx.x * 4;

    for (int idx = t; idx < 4 * 768; idx += 256)
        ps[idx] = pooled[(size_t)rr0 * 768 + idx];
    __syncthreads();

    for (int d = w; d < 768; d += 4) {
        float a0 = 0.f, a1 = 0.f, a2 = 0.f, a3 = 0.f;
#pragma unroll
        for (int i = 0; i < 3; ++i) {
            int c = i * 256 + lane * 4;
            float4 wv = *reinterpret_cast<const float4*>(Wo + (size_t)d * 768 + c);
            float4 p0 = *reinterpret_cast<const float4*>(&ps[0 * 768 + c]);
            float4 p1 = *reinterpret_cast<const float4*>(&ps[1 * 768 + c]);
            float4 p2 = *reinterpret_cast<const float4*>(&ps[2 * 768 + c]);
            float4 p3 = *reinterpret_cast<const float4*>(&ps[3 * 768 + c]);
            a0 += wv.x * p0.x + wv.y * p0.y + wv.z * p0.z + wv.w * p0.w;
            a1 += wv.x * p1.x + wv.y * p1.y + wv.z * p1.z + wv.w * p1.w;
            a2 += wv.x * p2.x + wv.y * p2.y + wv.z * p2.z + wv.w * p2.w;
            a3 += wv.x * p3.x + wv.y * p3.y + wv.z * p3.z + wv.w * p3.w;
        }
        a0 = wave_sum(a0); a1 = wave_sum(a1); a2 = wave_sum(a2); a3 = wave_sum(a3);
        if (lane == 0) {
            float bb = bo[d];
            out[(size_t)(rr0 + 0) * 768 + d] = a0 + bb;
            out[(size_t)(rr0 + 1) * 768 + d] = a1 + bb;
            out[(size_t)(rr0 + 2) * 768 + d] = a2 + bb;
            out[(size_t)(rr0 + 3) * 768 + d] = a3 + bb;
        }
    }
}

extern "C" void kernel_launch(void* const* d_in, const int* in_sizes, int n_in,
                              void* d_out, int out_size, void* d_ws, size_t ws_size,
                              hipStream_t stream) {
    const float* x  = (const float*)d_in[0];
    const float* Wq = (const float*)d_in[1];
    const float* bq = (const float*)d_in[2];
    const float* W0 = (const float*)d_in[3];
    const float* b0 = (const float*)d_in[4];
    const float* W1 = (const float*)d_in[5];
    const float* b1 = (const float*)d_in[6];
    const float* Wo = (const float*)d_in[7];
    const float* bo = (const float*)d_in[8];
    float* out = (float*)d_out;

    char* p = (char*)d_ws;
    size_t off = 0;
    auto carve = [&](size_t bytes) -> char* {
        char* r = p + off;
        off += (bytes + 255) & ~(size_t)255;
        return r;
    };
    float* ph     = (float*)carve((size_t)B_ * L_ * H_ * 4); // 3.1 MB
    float* pooled = (float*)carve((size_t)B_ * L_ * C_ * 4); // 1.6 MB

    const size_t xb_bytes  = (size_t)B_ * T_ * C_ * 2;       // 100.7 MB
    const size_t w0b_bytes = (size_t)B_ * H_ * C_ * 2;       // 75.5 MB
    const size_t wq_bytes  = (size_t)C_ * C_ * 2;            // 1.2 MB
    const size_t b0f_bytes = (size_t)B_ * H_ * 4;            // 0.2 MB

    const int n4x  = B_ * T_ * C_ / 4;
    const int n4wq = C_ * C_ / 4;
    const int n4w0 = B_ * H_ * C_ / 4;

    // fast path peak: ph+pooled + b0f + WqTb + Wfb + union(W0b, xb) ≈ 182 MB
    if (off + b0f_bytes + wq_bytes + w0b_bytes + xb_bytes + 1024 <= ws_size) {
        float* b0f  = (float*)carve(b0f_bytes);
        u16*   WqTb = (u16*)carve(wq_bytes);
        u16*   Wfb  = (u16*)carve(w0b_bytes);
        u16*   U    = (u16*)carve(xb_bytes);   // union region
        u16*   W0b  = U;                       // live: prep1 -> k_wf
        u16*   xb   = U;                       // live: cvt -> gemm9 (overwrites W0b)

        // 1) W0->bf16 + b0f (exact fp32) + Wq^T->bf16
        k_prep1<<<dim3(2048), 256, 0, stream>>>(Wq, WqTb, W0, W0b, bq, b0, b0f, 2016);
        // 2) Wf[b] = W0[b] @ Wq
        k_wf<<<dim3(C_ / 256, H_ / 256, B_), 512, 0, stream>>>(W0b, WqTb, Wfb);
        // 3) x -> bf16 (into the region W0b occupied; W0b is dead now)
        k_cvt<<<dim3(2048), 256, 0, stream>>>(x, xb, n4x);
        // 4) h = silu(x @ Wf^T + b0f), fused window-mean -> ph
        k_gemm9<1><<<dim3(H_ / 256, T_ / 256, B_), 512, 0, stream>>>(xb, Wfb, b0f, nullptr, ph);
    } else {
        // mid path (R8-proven): q = x@Wq^T via gemm9<0>, then gemm9<1>
        u16* qb  = (u16*)carve(xb_bytes);
        u16* Wqb = (u16*)carve(wq_bytes);
        u16* xb  = (u16*)carve(xb_bytes);
        u16* W0b = xb;   // alias: W0 converts after gemm9<0> consumed xb
        k_cvt<<<dim3(64), 256, 0, stream>>>(Wq, Wqb, n4wq);
        k_cvt<<<dim3(2048), 256, 0, stream>>>(x, xb, n4x);
        k_gemm9<0><<<dim3(C_ / 256, (B_ * T_) / 256), 512, 0, stream>>>(xb, Wqb, bq, qb, nullptr);
        k_cvt<<<dim3(2048), 256, 0, stream>>>(W0, W0b, n4w0);
        k_gemm9<1><<<dim3(H_ / 256, T_ / 256, B_), 512, 0, stream>>>(qb, W0b, b0, nullptr, ph);
    }

    k_3a<<<dim3(C_ / 16, B_), 256, 0, stream>>>(ph, W1, b1, pooled);
    k_3b<<<dim3(B_ * L_ / 4), 256, 0, stream>>>(pooled, Wo, bo, out);
}